// Round 3
// baseline (872.363 us; speedup 1.0000x reference)
//
#include <hip/hip_runtime.h>
#include <math.h>

#define NB    4
#define PP    1024
#define DD    32
#define MAXIT 30
#define NBLK  256     // phase-kernel grid
#define BTHR  256

// All state in module-scope device globals: no dependence on ws_size, no
// cooperative launch. Rewritten from scratch on every kernel_launch call.
__device__ float  g_C [NB*PP*PP];   // C[n][p][q], 16 MB
__device__ float  g_Ct[NB*PP*PP];   // C[n][q][p], 16 MB (for coalesced v-phase)
__device__ float  g_logmu[NB*PP], g_lognu[NB*PP];
__device__ float  g_u[NB*PP], g_v[NB*PP];
__device__ double g_errpart[MAXIT*NBLK];
__device__ int    g_done[MAXIT+1];
__device__ double g_costpart[NBLK];

// ---------------------------------------------------------------------------
__global__ void prep_kernel(const float* __restrict__ xw, const float* __restrict__ yw)
{
    const int t = threadIdx.x, lane = t & 63, wid = t >> 6;
    double sx = 0.0, sy = 0.0;
    for (int i = t; i < NB*PP; i += BTHR) { sx += (double)xw[i]; sy += (double)yw[i]; }
#pragma unroll
    for (int o = 32; o > 0; o >>= 1) { sx += __shfl_xor(sx, o); sy += __shfl_xor(sy, o); }
    __shared__ double a[4], b[4];
    if (lane == 0) { a[wid] = sx; b[wid] = sy; }
    __syncthreads();
    const double Sx = ((a[0]+a[1])+a[2])+a[3];
    const double Sy = ((b[0]+b[1])+b[2])+b[3];
    for (int i = t; i < NB*PP; i += BTHR) {
        g_logmu[i] = (float)log((double)xw[i]/Sx + 1e-8);
        g_lognu[i] = (float)log((double)yw[i]/Sy + 1e-8);
        g_u[i] = 0.f;
        g_v[i] = 0.f;
    }
    if (t <= MAXIT) g_done[t] = 0;
}

// ---------------------------------------------------------------------------
// Build C (blocks 0..511) and Ct (blocks 512..1023). Block owns 8 output rows.
__global__ void build_kernel(const float* __restrict__ x, const float* __restrict__ y)
{
    const int t = threadIdx.x;
    const int bid = blockIdx.x;
    const bool isC = bid < 512;
    const int b = isC ? bid : bid - 512;     // 0..511
    const int n = b >> 7;                    // 128 blocks per batch
    const int nbase = n << 10;
    const int gr0 = b << 3;                  // 8 global rows [gr0, gr0+8)

    __shared__ float rows[8][DD];
    {
        const int r = t >> 5, d = t & 31;
        const float* src = isC ? x : y;
        rows[r][d] = src[(gr0 + r) * DD + d];
    }
    __syncthreads();

    const float* other = isC ? y : x;
    float* dst = isC ? g_C : g_Ct;

    for (int c = 0; c < 4; ++c) {
        const int q = t + (c << 8);
        const float4* op = reinterpret_cast<const float4*>(other + ((size_t)(nbase + q) << 5));
        float o[DD];
#pragma unroll
        for (int j = 0; j < 8; ++j) {
            const float4 f = op[j];
            o[4*j+0] = f.x; o[4*j+1] = f.y; o[4*j+2] = f.z; o[4*j+3] = f.w;
        }
#pragma unroll
        for (int r = 0; r < 8; ++r) {
            float acc = 0.f;
#pragma unroll
            for (int d = 0; d < DD; ++d) {
                const float df = rows[r][d] - o[d];
                acc = fmaf(df, df, acc);
            }
            dst[((size_t)(gr0 + r) << 10) + q] = acc;
        }
    }
}

// ---------------------------------------------------------------------------
// u-phase: u_new[p] = 0.1*(log_mu[p] - lse_q( (v[q]-C[p,q])*10 )).
// 256 blocks x 256 thr; block owns 16 rows, each wave 4 rows.
__global__ void u_kernel(int it)
{
    const int t = threadIdx.x, lane = t & 63, wid = t >> 6;
    const int b = blockIdx.x;
    const int n = b >> 6;                    // 64 blocks per batch
    const int nbase = n << 10;
    const int done = g_done[it];

    const float4* Vp = reinterpret_cast<const float4*>(g_v + nbase);
    double du = 0.0;

    for (int rr = 0; rr < 4; ++rr) {
        const int gr = (b << 4) + (wid << 2) + rr;
        const float4* Cp = reinterpret_cast<const float4*>(g_C + ((size_t)gr << 10));
        float tv[16];
        float mx = -1e30f;
#pragma unroll
        for (int k = 0; k < 4; ++k) {
            const float4 cf = Cp[lane + (k << 6)];
            const float4 vf = Vp[lane + (k << 6)];
            tv[4*k+0] = (vf.x - cf.x) * 10.f;
            tv[4*k+1] = (vf.y - cf.y) * 10.f;
            tv[4*k+2] = (vf.z - cf.z) * 10.f;
            tv[4*k+3] = (vf.w - cf.w) * 10.f;
        }
#pragma unroll
        for (int i = 0; i < 16; ++i) mx = fmaxf(mx, tv[i]);
#pragma unroll
        for (int o = 32; o > 0; o >>= 1) mx = fmaxf(mx, __shfl_xor(mx, o));
        float s = 0.f;
#pragma unroll
        for (int i = 0; i < 16; ++i) s += __expf(tv[i] - mx);
#pragma unroll
        for (int o = 32; o > 0; o >>= 1) s += __shfl_xor(s, o);
        const float lse  = mx + __logf(s);
        const float unew = 0.1f * (g_logmu[gr] - lse);
        if (lane == 0) {
            du += fabs((double)unew - (double)g_u[gr]);
            if (!done) g_u[gr] = unew;       // freeze after convergence
        }
    }

    __shared__ double dred[4];
    if (lane == 0) dred[wid] = du;
    __syncthreads();
    if (t == 0) g_errpart[it * NBLK + b] = ((dred[0]+dred[1])+dred[2])+dred[3];
}

// ---------------------------------------------------------------------------
// v-phase: v_new[q] = 0.1*(log_nu[q] - lse_p( (u[p]-C[p,q])*10 )), via Ct rows.
// Block 0 additionally finalizes err(it) and latches g_done[it+1].
__global__ void v_kernel(int it)
{
    const int t = threadIdx.x, lane = t & 63, wid = t >> 6;
    const int b = blockIdx.x;
    const int n = b >> 6;
    const int nbase = n << 10;
    const int done = g_done[it];

    if (b == 0 && t < 64) {   // finalize err from u-phase partials (done flag for NEXT iter)
        const double* p = g_errpart + it * NBLK + (t << 2);
        double s = ((p[0] + p[1]) + p[2]) + p[3];
#pragma unroll
        for (int o = 32; o > 0; o >>= 1) s += __shfl_xor(s, o);
        if (t == 0) g_done[it + 1] = done | (s < 0.4);  // total<0.4 <=> mean<0.1
    }

    const float4* Up = reinterpret_cast<const float4*>(g_u + nbase);

    for (int rr = 0; rr < 4; ++rr) {
        const int gr = (b << 4) + (wid << 2) + rr;
        const float4* Cp = reinterpret_cast<const float4*>(g_Ct + ((size_t)gr << 10));
        float tv[16];
        float mx = -1e30f;
#pragma unroll
        for (int k = 0; k < 4; ++k) {
            const float4 cf = Cp[lane + (k << 6)];
            const float4 uf = Up[lane + (k << 6)];
            tv[4*k+0] = (uf.x - cf.x) * 10.f;
            tv[4*k+1] = (uf.y - cf.y) * 10.f;
            tv[4*k+2] = (uf.z - cf.z) * 10.f;
            tv[4*k+3] = (uf.w - cf.w) * 10.f;
        }
#pragma unroll
        for (int i = 0; i < 16; ++i) mx = fmaxf(mx, tv[i]);
#pragma unroll
        for (int o = 32; o > 0; o >>= 1) mx = fmaxf(mx, __shfl_xor(mx, o));
        float s = 0.f;
#pragma unroll
        for (int i = 0; i < 16; ++i) s += __expf(tv[i] - mx);
#pragma unroll
        for (int o = 32; o > 0; o >>= 1) s += __shfl_xor(s, o);
        const float lse  = mx + __logf(s);
        const float vnew = 0.1f * (g_lognu[gr] - lse);
        if (lane == 0 && !done) g_v[gr] = vnew;
    }
}

// ---------------------------------------------------------------------------
// cost = sum_pq exp((u_p + v_q - C_pq)*10) * C_pq, per batch (f64 partials).
__global__ void cost_kernel()
{
    const int t = threadIdx.x, lane = t & 63, wid = t >> 6;
    const int b = blockIdx.x;
    const int n = b >> 6;
    const int nbase = n << 10;

    const float4* Vp = reinterpret_cast<const float4*>(g_v + nbase);
    double part = 0.0;

    for (int rr = 0; rr < 4; ++rr) {
        const int gr = (b << 4) + (wid << 2) + rr;
        const float4* Cp = reinterpret_cast<const float4*>(g_C + ((size_t)gr << 10));
        const float ur = g_u[gr];
#pragma unroll
        for (int k = 0; k < 4; ++k) {
            const float4 cf = Cp[lane + (k << 6)];
            const float4 vf = Vp[lane + (k << 6)];
            part += (double)__expf((ur + vf.x - cf.x) * 10.f) * (double)cf.x;
            part += (double)__expf((ur + vf.y - cf.y) * 10.f) * (double)cf.y;
            part += (double)__expf((ur + vf.z - cf.z) * 10.f) * (double)cf.z;
            part += (double)__expf((ur + vf.w - cf.w) * 10.f) * (double)cf.w;
        }
    }
#pragma unroll
    for (int o = 32; o > 0; o >>= 1) part += __shfl_xor(part, o);
    __shared__ double red[4];
    if (lane == 0) red[wid] = part;
    __syncthreads();
    if (t == 0) g_costpart[b] = ((red[0]+red[1])+red[2])+red[3];
}

__global__ void out_kernel(float* __restrict__ out)
{
    const int t = threadIdx.x;   // 64 threads
#pragma unroll 1
    for (int n = 0; n < NB; ++n) {
        double s = g_costpart[(n << 6) + t];
#pragma unroll
        for (int o = 32; o > 0; o >>= 1) s += __shfl_xor(s, o);
        if (t == 0) out[n] = (float)s;
    }
}

// ---------------------------------------------------------------------------
extern "C" void kernel_launch(void* const* d_in, const int* in_sizes, int n_in,
                              void* d_out, int out_size, void* d_ws, size_t ws_size,
                              hipStream_t stream)
{
    (void)in_sizes; (void)n_in; (void)out_size; (void)d_ws; (void)ws_size;
    const float* x  = (const float*)d_in[0];
    const float* y  = (const float*)d_in[1];
    const float* xw = (const float*)d_in[2];
    const float* yw = (const float*)d_in[3];
    float* out = (float*)d_out;

    hipLaunchKernelGGL(prep_kernel,  dim3(1),    dim3(BTHR), 0, stream, xw, yw);
    hipLaunchKernelGGL(build_kernel, dim3(1024), dim3(BTHR), 0, stream, x, y);
    for (int it = 0; it < MAXIT; ++it) {
        hipLaunchKernelGGL(u_kernel, dim3(NBLK), dim3(BTHR), 0, stream, it);
        hipLaunchKernelGGL(v_kernel, dim3(NBLK), dim3(BTHR), 0, stream, it);
    }
    hipLaunchKernelGGL(cost_kernel, dim3(NBLK), dim3(BTHR), 0, stream);
    hipLaunchKernelGGL(out_kernel,  dim3(1),    dim3(64),   0, stream, out);
}

// Round 4
// 338.182 us; speedup vs baseline: 2.5796x; 2.5796x over previous
//
#include <hip/hip_runtime.h>
#include <math.h>

#define NB    4
#define PP    1024
#define DD    32
#define MAXIT 30
#define PBLK  1024    // phase-kernel grid (u/v/cost): 1 row per wave
#define BTHR  256

// All state in module-scope device globals: no dependence on ws_size, no
// cooperative launch. Rewritten from scratch on every kernel_launch call.
__device__ float  g_C [NB*PP*PP];   // C[n][p][q], 16 MB
__device__ float  g_Ct[NB*PP*PP];   // C[n][q][p], 16 MB (coalesced v-phase)
__device__ float  g_logmu[NB*PP], g_lognu[NB*PP];
__device__ float  g_u[NB*PP], g_v[NB*PP];
__device__ double g_errpart[MAXIT*PBLK];
__device__ int    g_done[MAXIT+1];
__device__ double g_costpart[PBLK];

// ---------------------------------------------------------------------------
__global__ __launch_bounds__(BTHR)
void prep_kernel(const float* __restrict__ xw, const float* __restrict__ yw)
{
    const int t = threadIdx.x, lane = t & 63, wid = t >> 6;
    double sx = 0.0, sy = 0.0;
    for (int i = t; i < NB*PP; i += BTHR) { sx += (double)xw[i]; sy += (double)yw[i]; }
#pragma unroll
    for (int o = 32; o > 0; o >>= 1) { sx += __shfl_xor(sx, o); sy += __shfl_xor(sy, o); }
    __shared__ double a[4], b[4];
    if (lane == 0) { a[wid] = sx; b[wid] = sy; }
    __syncthreads();
    const double Sx = ((a[0]+a[1])+a[2])+a[3];
    const double Sy = ((b[0]+b[1])+b[2])+b[3];
    for (int i = t; i < NB*PP; i += BTHR) {
        g_logmu[i] = (float)log((double)xw[i]/Sx + 1e-8);
        g_lognu[i] = (float)log((double)yw[i]/Sy + 1e-8);
        g_u[i] = 0.f;
        g_v[i] = 0.f;
    }
    if (t <= MAXIT) g_done[t] = 0;
}

// ---------------------------------------------------------------------------
// Build C (blocks 0..511) and Ct (blocks 512..1023). Block owns 8 output rows
// staged in LDS; thread t owns cols {t, t+256, t+512, t+768} x all 8 rows in
// register accumulators (fully static indexing -> no scratch).
__global__ __launch_bounds__(BTHR)
void build_kernel(const float* __restrict__ x, const float* __restrict__ y)
{
    const int t = threadIdx.x;
    const int bid = blockIdx.x;
    const bool isC = bid < 512;
    const int b = isC ? bid : bid - 512;     // 0..511
    const int n = b >> 7;                    // 128 blocks per batch
    const int nbase = n << 10;
    const int gr0 = b << 3;                  // 8 global rows [gr0, gr0+8)

    __shared__ float rows[8][DD];
    {
        const int r = t >> 5, d = t & 31;
        const float* src = isC ? x : y;
        rows[r][d] = src[(gr0 + r) * DD + d];
    }
    __syncthreads();

    const float* other = isC ? y : x;
    float* dst = isC ? g_C : g_Ct;

    const float4* op0 = reinterpret_cast<const float4*>(other + ((size_t)(nbase + t      ) << 5));
    const float4* op1 = reinterpret_cast<const float4*>(other + ((size_t)(nbase + t + 256) << 5));
    const float4* op2 = reinterpret_cast<const float4*>(other + ((size_t)(nbase + t + 512) << 5));
    const float4* op3 = reinterpret_cast<const float4*>(other + ((size_t)(nbase + t + 768) << 5));

    float acc0[8], acc1[8], acc2[8], acc3[8];
#pragma unroll
    for (int r = 0; r < 8; ++r) { acc0[r] = 0.f; acc1[r] = 0.f; acc2[r] = 0.f; acc3[r] = 0.f; }

#pragma unroll
    for (int j = 0; j < 8; ++j) {
        const float4 f0 = op0[j];
        const float4 f1 = op1[j];
        const float4 f2 = op2[j];
        const float4 f3 = op3[j];
#pragma unroll
        for (int r = 0; r < 8; ++r) {
            const float4 rv = *reinterpret_cast<const float4*>(&rows[r][4*j]);
            float d;
            d = rv.x - f0.x; acc0[r] = fmaf(d, d, acc0[r]);
            d = rv.y - f0.y; acc0[r] = fmaf(d, d, acc0[r]);
            d = rv.z - f0.z; acc0[r] = fmaf(d, d, acc0[r]);
            d = rv.w - f0.w; acc0[r] = fmaf(d, d, acc0[r]);
            d = rv.x - f1.x; acc1[r] = fmaf(d, d, acc1[r]);
            d = rv.y - f1.y; acc1[r] = fmaf(d, d, acc1[r]);
            d = rv.z - f1.z; acc1[r] = fmaf(d, d, acc1[r]);
            d = rv.w - f1.w; acc1[r] = fmaf(d, d, acc1[r]);
            d = rv.x - f2.x; acc2[r] = fmaf(d, d, acc2[r]);
            d = rv.y - f2.y; acc2[r] = fmaf(d, d, acc2[r]);
            d = rv.z - f2.z; acc2[r] = fmaf(d, d, acc2[r]);
            d = rv.w - f2.w; acc2[r] = fmaf(d, d, acc2[r]);
            d = rv.x - f3.x; acc3[r] = fmaf(d, d, acc3[r]);
            d = rv.y - f3.y; acc3[r] = fmaf(d, d, acc3[r]);
            d = rv.z - f3.z; acc3[r] = fmaf(d, d, acc3[r]);
            d = rv.w - f3.w; acc3[r] = fmaf(d, d, acc3[r]);
        }
    }
#pragma unroll
    for (int r = 0; r < 8; ++r) {
        float* row = dst + (((size_t)(gr0 + r)) << 10);
        row[t      ] = acc0[r];
        row[t + 256] = acc1[r];
        row[t + 512] = acc2[r];
        row[t + 768] = acc3[r];
    }
}

// ---------------------------------------------------------------------------
// u-phase: u_new[p] = 0.1*(log_mu[p] - lse_q((v[q]-C[p,q])*10)).
// 1024 blocks x 256 thr; one row per wave (4 rows per block).
__global__ __launch_bounds__(BTHR)
void u_kernel(int it)
{
    const int t = threadIdx.x, lane = t & 63, wid = t >> 6;
    const int b = blockIdx.x;
    const int n = b >> 8;                    // 256 blocks per batch
    const int nbase = n << 10;
    const int done = g_done[it];
    const int gr = (b << 2) + wid;

    const float4* Vp = reinterpret_cast<const float4*>(g_v + nbase);
    const float4* Cp = reinterpret_cast<const float4*>(g_C + ((size_t)gr << 10));

    float tv[16];
    float mx = -1e30f;
#pragma unroll
    for (int k = 0; k < 4; ++k) {
        const float4 cf = Cp[lane + (k << 6)];
        const float4 vf = Vp[lane + (k << 6)];
        tv[4*k+0] = (vf.x - cf.x) * 10.f;
        tv[4*k+1] = (vf.y - cf.y) * 10.f;
        tv[4*k+2] = (vf.z - cf.z) * 10.f;
        tv[4*k+3] = (vf.w - cf.w) * 10.f;
    }
#pragma unroll
    for (int i = 0; i < 16; ++i) mx = fmaxf(mx, tv[i]);
#pragma unroll
    for (int o = 32; o > 0; o >>= 1) mx = fmaxf(mx, __shfl_xor(mx, o));
    float s = 0.f;
#pragma unroll
    for (int i = 0; i < 16; ++i) s += __expf(tv[i] - mx);
#pragma unroll
    for (int o = 32; o > 0; o >>= 1) s += __shfl_xor(s, o);
    const float lse  = mx + __logf(s);
    const float unew = 0.1f * (g_logmu[gr] - lse);

    __shared__ double dred[4];
    if (lane == 0) {
        dred[wid] = fabs((double)unew - (double)g_u[gr]);
        if (!done) g_u[gr] = unew;           // freeze after convergence
    }
    __syncthreads();
    if (t == 0) g_errpart[it * PBLK + b] = ((dred[0]+dred[1])+dred[2])+dred[3];
}

// ---------------------------------------------------------------------------
// v-phase: v_new[q] = 0.1*(log_nu[q] - lse_p((u[p]-C[p,q])*10)), via Ct rows.
// Block 0 additionally finalizes err(it) and latches g_done[it+1].
__global__ __launch_bounds__(BTHR)
void v_kernel(int it)
{
    const int t = threadIdx.x, lane = t & 63, wid = t >> 6;
    const int b = blockIdx.x;
    const int n = b >> 8;
    const int nbase = n << 10;
    const int done = g_done[it];

    if (b == 0) {   // finalize err from u-phase partials -> done flag for it+1
        const double* p = g_errpart + it * PBLK;
        double s = ((p[t] + p[t+256]) + p[t+512]) + p[t+768];
#pragma unroll
        for (int o = 32; o > 0; o >>= 1) s += __shfl_xor(s, o);
        __shared__ double sred[4];
        if (lane == 0) sred[wid] = s;
        __syncthreads();
        if (t == 0) {
            const double tot = ((sred[0]+sred[1])+sred[2])+sred[3];
            g_done[it + 1] = done | (tot < 0.4);   // total<0.4 <=> mean<0.1
        }
    }

    const int gr = (b << 2) + wid;
    const float4* Up = reinterpret_cast<const float4*>(g_u + nbase);
    const float4* Cp = reinterpret_cast<const float4*>(g_Ct + ((size_t)gr << 10));

    float tv[16];
    float mx = -1e30f;
#pragma unroll
    for (int k = 0; k < 4; ++k) {
        const float4 cf = Cp[lane + (k << 6)];
        const float4 uf = Up[lane + (k << 6)];
        tv[4*k+0] = (uf.x - cf.x) * 10.f;
        tv[4*k+1] = (uf.y - cf.y) * 10.f;
        tv[4*k+2] = (uf.z - cf.z) * 10.f;
        tv[4*k+3] = (uf.w - cf.w) * 10.f;
    }
#pragma unroll
    for (int i = 0; i < 16; ++i) mx = fmaxf(mx, tv[i]);
#pragma unroll
    for (int o = 32; o > 0; o >>= 1) mx = fmaxf(mx, __shfl_xor(mx, o));
    float s = 0.f;
#pragma unroll
    for (int i = 0; i < 16; ++i) s += __expf(tv[i] - mx);
#pragma unroll
    for (int o = 32; o > 0; o >>= 1) s += __shfl_xor(s, o);
    const float lse  = mx + __logf(s);
    const float vnew = 0.1f * (g_lognu[gr] - lse);
    if (lane == 0 && !done) g_v[gr] = vnew;
}

// ---------------------------------------------------------------------------
// cost = sum_pq exp((u_p + v_q - C_pq)*10) * C_pq, per batch (f64 partials).
__global__ __launch_bounds__(BTHR)
void cost_kernel()
{
    const int t = threadIdx.x, lane = t & 63, wid = t >> 6;
    const int b = blockIdx.x;
    const int n = b >> 8;
    const int nbase = n << 10;
    const int gr = (b << 2) + wid;

    const float4* Vp = reinterpret_cast<const float4*>(g_v + nbase);
    const float4* Cp = reinterpret_cast<const float4*>(g_C + ((size_t)gr << 10));
    const float ur = g_u[gr];

    double part = 0.0;
#pragma unroll
    for (int k = 0; k < 4; ++k) {
        const float4 cf = Cp[lane + (k << 6)];
        const float4 vf = Vp[lane + (k << 6)];
        part += (double)__expf((ur + vf.x - cf.x) * 10.f) * (double)cf.x;
        part += (double)__expf((ur + vf.y - cf.y) * 10.f) * (double)cf.y;
        part += (double)__expf((ur + vf.z - cf.z) * 10.f) * (double)cf.z;
        part += (double)__expf((ur + vf.w - cf.w) * 10.f) * (double)cf.w;
    }
#pragma unroll
    for (int o = 32; o > 0; o >>= 1) part += __shfl_xor(part, o);
    __shared__ double red[4];
    if (lane == 0) red[wid] = part;
    __syncthreads();
    if (t == 0) g_costpart[b] = ((red[0]+red[1])+red[2])+red[3];
}

__global__ __launch_bounds__(64)
void out_kernel(float* __restrict__ out)
{
    const int t = threadIdx.x;   // 64 threads
#pragma unroll 1
    for (int n = 0; n < NB; ++n) {
        const double* cp = g_costpart + (n << 8);
        double s = ((cp[t] + cp[t+64]) + cp[t+128]) + cp[t+192];
#pragma unroll
        for (int o = 32; o > 0; o >>= 1) s += __shfl_xor(s, o);
        if (t == 0) out[n] = (float)s;
    }
}

// ---------------------------------------------------------------------------
extern "C" void kernel_launch(void* const* d_in, const int* in_sizes, int n_in,
                              void* d_out, int out_size, void* d_ws, size_t ws_size,
                              hipStream_t stream)
{
    (void)in_sizes; (void)n_in; (void)out_size; (void)d_ws; (void)ws_size;
    const float* x  = (const float*)d_in[0];
    const float* y  = (const float*)d_in[1];
    const float* xw = (const float*)d_in[2];
    const float* yw = (const float*)d_in[3];
    float* out = (float*)d_out;

    hipLaunchKernelGGL(prep_kernel,  dim3(1),    dim3(BTHR), 0, stream, xw, yw);
    hipLaunchKernelGGL(build_kernel, dim3(1024), dim3(BTHR), 0, stream, x, y);
    for (int it = 0; it < MAXIT; ++it) {
        hipLaunchKernelGGL(u_kernel, dim3(PBLK), dim3(BTHR), 0, stream, it);
        hipLaunchKernelGGL(v_kernel, dim3(PBLK), dim3(BTHR), 0, stream, it);
    }
    hipLaunchKernelGGL(cost_kernel, dim3(PBLK), dim3(BTHR), 0, stream);
    hipLaunchKernelGGL(out_kernel,  dim3(1),    dim3(64),   0, stream, out);
}